// Round 6
// baseline (661.396 us; speedup 1.0000x reference)
//
#include <hip/hip_runtime.h>
#include <hip/hip_bf16.h>

#define BB 8192
#define TT 40
#define HH 128
#define CC 102
#define VV 4450

#define L2E  1.4426950408889634f
#define L2E2 2.8853900817779268f

typedef __attribute__((ext_vector_type(8))) short short8;
typedef __attribute__((ext_vector_type(4))) float f4;

__device__ __forceinline__ float rcpf_(float x) { return __builtin_amdgcn_rcpf(x); }
__device__ __forceinline__ float exp2f_(float x) { return __builtin_amdgcn_exp2f(x); }

__device__ __forceinline__ unsigned short f2bf(float x) {
    union { float f; unsigned u; } v; v.f = x;
    unsigned r = v.u + 0x7FFFu + ((v.u >> 16) & 1u);
    return (unsigned short)(r >> 16);
}
__device__ __forceinline__ float bf2f(unsigned short h) {
    union { float f; unsigned u; } v; v.u = ((unsigned)h) << 16; return v.f;
}
__device__ __forceinline__ short8 u4s8(uint4 v) { return *(short8*)&v; }

// packed f32x2 -> bf16x2 (RNE), S0 -> low 16, S1 -> high 16
__device__ __forceinline__ unsigned cvtpk_bf16(float lo, float hi) {
    unsigned r;
    asm("v_cvt_pk_bf16_f32 %0, %1, %2" : "=v"(r) : "v"(lo), "v"(hi));
    return r;
}
// hi/lo split of two floats: H = packed bf16 hi parts, L = packed bf16 residuals
__device__ __forceinline__ void split2(float a, float b, unsigned& H, unsigned& L) {
    H = cvtpk_bf16(a, b);
    float ra = __uint_as_float(H << 16);
    float rb = __uint_as_float(H & 0xFFFF0000u);
    L = cvtpk_bf16(a - ra, b - rb);
}

struct __attribute__((aligned(4))) G3 { float r, z, n; };

#define MFMA16(acc, a, b) acc = __builtin_amdgcn_mfma_f32_16x16x32_bf16(a, b, acc, 0, 0, 0)

// ---------- prep 1: split fp32 array into bf16 hi/lo (unscaled, for W_ih) ----------
__global__ __launch_bounds__(256) void prep_bf16split(const float* __restrict__ W,
                                                      unsigned short* __restrict__ hi,
                                                      unsigned short* __restrict__ lo, int n) {
    int i = blockIdx.x * 256 + threadIdx.x;
    if (i < n) {
        float x = W[i];
        unsigned short h = f2bf(x);
        hi[i] = h;
        lo[i] = f2bf(x - bf2f(h));
    }
}

// ---------- prep 1a: split W_hh with per-gate exp2 pre-scale ----------
// rows [0,256) (r,z gates): * log2e  -> sigmoid via exp2
// rows [256,384) (n gate) : * 2*log2e -> tanh via exp2
__global__ __launch_bounds__(256) void prep_whh(const float* __restrict__ W,
                                                unsigned short* __restrict__ hi,
                                                unsigned short* __restrict__ lo) {
    int i = blockIdx.x * 256 + threadIdx.x;
    if (i < 384 * HH) {
        float s = (i < 256 * HH) ? L2E : L2E2;
        float x = W[i] * s;
        unsigned short h = f2bf(x);
        hi[i] = h;
        lo[i] = f2bf(x - bf2f(h));
    }
}

// ---------- prep 1b: split W_cls into bf16 hi/lo, padded to 112 rows ----------
__global__ __launch_bounds__(256) void prep_wcls(const float* __restrict__ W,
                                                 unsigned short* __restrict__ hi,
                                                 unsigned short* __restrict__ lo) {
    int i = blockIdx.x * 256 + threadIdx.x;
    if (i < 112 * HH) {
        int r = i >> 7;
        float x = (r < CC) ? W[i] : 0.f;
        unsigned short h = f2bf(x);
        hi[i] = h;
        lo[i] = f2bf(x - bf2f(h));
    }
}

// ---------- prep 2: G[src][v][j][gate] = (emb[v] @ W_ih^T + biases) * gate_scale ----------
// Output layout: G[v*384 + j*3 + g]  (j = hidden col 0..127, g = gate r/z/n)
__global__ __launch_bounds__(256) void prep_G_mfma(
    const float* __restrict__ emb_a, const float* __restrict__ emb_c,
    const unsigned short* __restrict__ WihH, const unsigned short* __restrict__ WihL,
    const float* __restrict__ b_ih, const float* __restrict__ b_hh,
    float* __restrict__ G)
{
    __shared__ uint4 se[2][32][16];   // [hi/lo][row][swizzled 16B k-chunk]

    const int tid = threadIdx.x;
    const int src = blockIdx.y;
    const float* emb = src ? emb_c : emb_a;
    const int v0 = blockIdx.x * 32;

    const int lane = tid & 63;
    const int w = tid >> 6;
    const int mcol = lane & 15;
    const int quad = lane >> 4;

    // stage emb tile -> bf16 hi/lo (xor-swizzled: phys chunk = chunk ^ (row&15))
#pragma unroll
    for (int i = 0; i < 4; ++i) {
        int task = tid + 256 * i;       // 0..1023 = 32 rows x 32 float4
        int row = task >> 5, q = task & 31;
        int v = v0 + row;
        float4 x = make_float4(0.f, 0.f, 0.f, 0.f);
        if (v < VV) x = ((const float4*)(emb + (size_t)v * HH))[q];
        uint2 Hw, Lw;
        split2(x.x, x.y, Hw.x, Lw.x);
        split2(x.z, x.w, Hw.y, Lw.y);
        int phys = (q >> 1) ^ (row & 15);
        ((uint2*)&se[0][row][phys])[q & 1] = Hw;
        ((uint2*)&se[1][row][phys])[q & 1] = Lw;
    }

    // per-lane biases for the 6 output col groups
    float bias[6];
#pragma unroll
    for (int n6 = 0; n6 < 6; ++n6) {
        int c = w * 96 + n6 * 16 + mcol;
        bias[n6] = b_ih[c] + (c < 256 ? b_hh[c] : 0.f);
    }

    f4 acc[2][6];
#pragma unroll
    for (int mt = 0; mt < 2; ++mt)
#pragma unroll
        for (int n6 = 0; n6 < 6; ++n6) acc[mt][n6] = (f4){0.f, 0.f, 0.f, 0.f};

    __syncthreads();

#pragma unroll
    for (int kk = 0; kk < 4; ++kk) {
        uint4 bH[6], bL[6];
#pragma unroll
        for (int n6 = 0; n6 < 6; ++n6) {
            int rowc = w * 96 + n6 * 16 + mcol;
            bH[n6] = *((const uint4*)WihH + rowc * 16 + kk * 4 + quad);
            bL[n6] = *((const uint4*)WihL + rowc * 16 + kk * 4 + quad);
        }
#pragma unroll
        for (int mt = 0; mt < 2; ++mt) {
            int m = mt * 16 + mcol;
            int phys = (kk * 4 + quad) ^ mcol;
            short8 ah = u4s8(se[0][m][phys]);
            short8 al = u4s8(se[1][m][phys]);
#pragma unroll
            for (int n6 = 0; n6 < 6; ++n6) {
                MFMA16(acc[mt][n6], ah, u4s8(bH[n6]));
                MFMA16(acc[mt][n6], ah, u4s8(bL[n6]));
                MFMA16(acc[mt][n6], al, u4s8(bH[n6]));
            }
        }
    }

    float* gout = G + (size_t)src * VV * 384;
#pragma unroll
    for (int mt = 0; mt < 2; ++mt)
#pragma unroll
        for (int r = 0; r < 4; ++r) {
            int m = mt * 16 + quad * 4 + r;
            int v = v0 + m;
            if (v < VV) {
#pragma unroll
                for (int n6 = 0; n6 < 6; ++n6) {
                    int c = w * 96 + n6 * 16 + mcol;
                    int g = c >> 7, jj = c & 127;
                    float scl = (g < 2) ? L2E : L2E2;
                    gout[(size_t)v * 384 + jj * 3 + g] = (acc[mt][n6][r] + bias[n6]) * scl;
                }
            }
        }
}

// ---------- main GRU: M=16 per block, 1024 blocks ----------
// R5 plateau analysis: ~70% combined issue but step-slot >> issued cycles ->
// dependency-latency-bound (LDS write -> barrier -> ds_read -> 12-deep MFMA
// chain -> act chain). Halving the batch tile (M=32 -> 16) halves every serial
// chain per step (36 MFMA, 4 act-h, 8 ds_read, 4 gathers per wave) while
// doubling the number of independent recurrences per CU. Total work constant.
// State shrinks (acc 12, gc 12, hreg 4 + weights 96) -> VGPR <= R5's 108 under
// the proven (512,2). XCD-src parity kept: src = bid&1.
__global__ __launch_bounds__(512, 2) void gru_mfma(
    const int* __restrict__ ids, const float* __restrict__ G,
    const __hip_bfloat16* __restrict__ Whi, const __hip_bfloat16* __restrict__ Wlo,
    const float* __restrict__ b_hh, float* __restrict__ ha, float* __restrict__ hc)
{
    __shared__ uint4 sh[2][2][16][16];   // [buf][hi/lo][row][chunk] = 16 KiB
    __shared__ int sids[16 * TT];

    const int tid = threadIdx.x;
    const int src = blockIdx.x & 1;          // XCD parity = src parity
    const int b0 = (blockIdx.x >> 1) * 16;
    const float* Gs = G + (size_t)src * VV * 384;
    float* hout = src ? hc : ha;

    const int lane = tid & 63;
    const int w = tid >> 6;
    const int nc0 = w * 16;
    const int mcol = lane & 15;
    const int quad = lane >> 4;

    for (int idx = tid; idx < 16 * TT; idx += 512)
        sids[idx] = ids[b0 * TT + idx];

    {
        uint4 z; z.x = z.y = z.z = z.w = 0u;
        uint4* p = &sh[0][0][0][0];
        if (tid < 2 * 16 * 16) p[tid] = z;   // zero h(t=0), both hi/lo of buf 0
    }

    short8 bh[3][4], bl[3][4];
#pragma unroll
    for (int g = 0; g < 3; ++g)
#pragma unroll
        for (int kk = 0; kk < 4; ++kk) {
            int row = g * 128 + nc0 + mcol;
            uint4 vh = *((const uint4*)Whi + row * 16 + kk * 4 + quad);
            uint4 vl = *((const uint4*)Wlo + row * 16 + kk * 4 + quad);
            bh[g][kk] = u4s8(vh);
            bl[g][kk] = u4s8(vl);
        }

    const int j = nc0 + mcol;
    const float bhn = L2E2 * b_hh[256 + j];
    const float* gbase = Gs + 3 * j;

    f4 hreg = (f4){0.f, 0.f, 0.f, 0.f};

    __syncthreads();

    G3 gc[4];
#pragma unroll
    for (int reg = 0; reg < 4; ++reg) {
        int m = quad * 4 + reg;
        int id = sids[m * TT + 0];
        gc[reg] = *(const G3*)(gbase + (size_t)id * 384);
    }

    const int s_slot = j >> 3;
    const int jb = j & 7;

    int buf = 0;
#pragma unroll 1
    for (int t = 0; t < TT; ++t) {
        f4 acc[3];
#pragma unroll
        for (int g = 0; g < 3; ++g) acc[g] = (f4){0.f, 0.f, 0.f, 0.f};

#pragma unroll
        for (int kk = 0; kk < 4; ++kk) {
            int phys = (kk * 4 + quad) ^ mcol;
            uint4 avh = sh[buf][0][mcol][phys];
            uint4 avl = sh[buf][1][mcol][phys];
            short8 ah = u4s8(avh), al = u4s8(avl);
#pragma unroll
            for (int g = 0; g < 3; ++g) {
                MFMA16(acc[g], ah, bh[g][kk]);
                MFMA16(acc[g], ah, bl[g][kk]);
                MFMA16(acc[g], al, bh[g][kk]);
            }
        }

        const int nbuf = buf ^ 1;
        float hv4[4];
#pragma unroll
        for (int reg = 0; reg < 4; ++reg) {
            G3 g = gc[reg];
            // inputs pre-scaled by log2e (r,z) / 2*log2e (n) -> raw exp2
            float rr = rcpf_(1.f + exp2f_(-(acc[0][reg] + g.r)));
            float zz = rcpf_(1.f + exp2f_(-(acc[1][reg] + g.z)));
            float y  = g.n + rr * (acc[2][reg] + bhn);
            float nn = 1.f - 2.f * rcpf_(exp2f_(y) + 1.f);
            float hv = fmaf(zz, hreg[reg] - nn, nn);
            hreg[reg] = hv;
            hv4[reg] = hv;

            int m = quad * 4 + reg;
            hout[((size_t)(b0 + m) * TT + t) * HH + j] = hv;
        }
#pragma unroll
        for (int pr = 0; pr < 2; ++pr) {
            unsigned Hp, Lp;
            split2(hv4[pr * 2], hv4[pr * 2 + 1], Hp, Lp);
#pragma unroll
            for (int k = 0; k < 2; ++k) {
                int m = quad * 4 + pr * 2 + k;
                int phys = s_slot ^ m;
                unsigned short hb = (unsigned short)(k ? (Hp >> 16) : Hp);
                unsigned short lb = (unsigned short)(k ? (Lp >> 16) : Lp);
                ((unsigned short*)&sh[nbuf][0][m][phys])[jb] = hb;
                ((unsigned short*)&sh[nbuf][1][m][phys])[jb] = lb;
            }
        }

        if (t < TT - 1) {
#pragma unroll
            for (int reg = 0; reg < 4; ++reg) {
                int m = quad * 4 + reg;
                int id = sids[m * TT + t + 1];
                gc[reg] = *(const G3*)(gbase + (size_t)id * 384);
            }
        }
        __syncthreads();
        buf ^= 1;
    }
}

// ---------- attention + classifier, MFMA version ----------
#define AT_SHA     0
#define AT_SHA_LO  12288
#define AT_SHCT    24576
#define AT_SHCT_LO 40960
#define AT_SM      57344
#define AT_SW      66752
#define AT_SW_LO   72896
#define AT_PARTM   79040
#define AT_PARTD   79808
#define AT_SMX     80576
#define AT_SDI     80768
#define AT_TOTAL   80960

__global__ __launch_bounds__(256, 2) void attn_cls_mfma(
    const float* __restrict__ ha, const float* __restrict__ hc,
    const unsigned short* __restrict__ WcH, const unsigned short* __restrict__ WcL,
    const float* __restrict__ b_cls, float* __restrict__ out)
{
    __shared__ __attribute__((aligned(16))) char smem[AT_TOTAL];
    const int tid = threadIdx.x;
    const int lane = tid & 63;
    const int w = tid >> 6;
    const int quad = lane >> 4;
    const int col = lane & 15;
    const size_t b = blockIdx.x;

    float* sm    = (float*)(smem + AT_SM);
    float* slog  = (float*)(smem + AT_SM);
    float* partM = (float*)(smem + AT_PARTM);
    float* partD = (float*)(smem + AT_PARTD);
    float* sMX   = (float*)(smem + AT_SMX);
    float* sDI   = (float*)(smem + AT_SDI);

    const int ntc0 = (w < 3) ? w : 3;
    const int ntc1 = (w < 3) ? w + 4 : 3;
    uint4 bw[2][4][2];
    float bcv[2];
    {
        int nts[2] = {ntc0, ntc1};
#pragma unroll
        for (int which = 0; which < 2; ++which) {
            int row = nts[which] * 16 + col;
#pragma unroll
            for (int kk = 0; kk < 4; ++kk) {
                bw[which][kk][0] = *((const uint4*)WcH + row * 16 + kk * 4 + quad);
                bw[which][kk][1] = *((const uint4*)WcL + row * 16 + kk * 4 + quad);
            }
            bcv[which] = (row < CC) ? b_cls[row] : 0.f;
        }
    }

    {
        const float4* hab = (const float4*)(ha + b * TT * HH);
#pragma unroll
        for (int i = 0; i < 5; ++i) {
            int f4i = tid + 256 * i;
            int row = f4i >> 5, q = f4i & 31;
            float4 v = hab[f4i];
            uint2 Hw, Lw;
            split2(v.x, v.y, Hw.x, Lw.x);
            split2(v.z, v.w, Hw.y, Lw.y);
            int phys = (q >> 1) ^ (row & 15);
            int off = row * 256 + phys * 16 + (q & 1) * 8;
            *(uint2*)(smem + AT_SHA + off) = Hw;
            *(uint2*)(smem + AT_SHA_LO + off) = Lw;
        }
        if (tid < 128) {
            int row = 40 + (tid >> 4), c = tid & 15;
            uint4 z; z.x = z.y = z.z = z.w = 0u;
            *(uint4*)(smem + AT_SHA + row * 256 + c * 16) = z;
            *(uint4*)(smem + AT_SHA_LO + row * 256 + c * 16) = z;
        }
        const float* hcb = hc + b * TT * HH;
        for (int task = tid; task < 640; task += 256) {
            int h = task & 127, c = task >> 7;
            float x[8];
#pragma unroll
            for (int jj = 0; jj < 8; ++jj) x[jj] = hcb[(c * 8 + jj) * HH + h];
            uint4 Hq, Lq;
            split2(x[0], x[1], Hq.x, Lq.x);
            split2(x[2], x[3], Hq.y, Lq.y);
            split2(x[4], x[5], Hq.z, Lq.z);
            split2(x[6], x[7], Hq.w, Lq.w);
            int phys = c ^ (h & 7);
            *(uint4*)(smem + AT_SHCT + h * 128 + phys * 16) = Hq;
            *(uint4*)(smem + AT_SHCT_LO + h * 128 + phys * 16) = Lq;
        }
        for (int task = tid; task < 384; task += 256) {
            int h = task & 127, c = 5 + (task >> 7);
            int phys = c ^ (h & 7);
            uint4 z; z.x = z.y = z.z = z.w = 0u;
            *(uint4*)(smem + AT_SHCT + h * 128 + phys * 16) = z;
            *(uint4*)(smem + AT_SHCT_LO + h * 128 + phys * 16) = z;
        }
    }
    __syncthreads();

    if (w < 3) {
        const int mt = w;
        uint4 aH[4], aL[4];
#pragma unroll
        for (int kk = 0; kk < 4; ++kk) {
            int phys = (kk * 4 + quad) ^ col;
            int off = (mt * 16 + col) * 256 + phys * 16;
            aH[kk] = *(uint4*)(smem + AT_SHA + off);
            aL[kk] = *(uint4*)(smem + AT_SHA_LO + off);
        }
        f4 acc[3];
#pragma unroll
        for (int nt = 0; nt < 3; ++nt) acc[nt] = (f4){0.f, 0.f, 0.f, 0.f};
#pragma unroll
        for (int kk = 0; kk < 4; ++kk) {
            short8 ah = u4s8(aH[kk]), al = u4s8(aL[kk]);
#pragma unroll
            for (int nt = 0; nt < 3; ++nt) {
                int phys = (kk * 4 + quad) ^ col;
                int off = (nt * 16 + col) * 256 + phys * 16;
                short8 bH = u4s8(*(uint4*)(smem + AT_SHA + off));
                short8 bL = u4s8(*(uint4*)(smem + AT_SHA_LO + off));
                MFMA16(acc[nt], ah, bH);
                MFMA16(acc[nt], ah, bL);
                MFMA16(acc[nt], al, bH);
            }
        }
#pragma unroll
        for (int nt = 0; nt < 3; ++nt)
#pragma unroll
            for (int r = 0; r < 4; ++r)
                sm[(mt * 16 + quad * 4 + r) * 49 + nt * 16 + col] = acc[nt][r];
    }
    __syncthreads();

    if (tid < 160) {
        int t = tid >> 2, p = tid & 3;
        const float* row = sm + t * 49 + p * 10;
        float M = row[0];
#pragma unroll
        for (int i = 1; i < 10; ++i) M = fmaxf(M, row[i]);
        float D = 0.f;
#pragma unroll
        for (int i = 0; i < 10; ++i) D += __expf(row[i] - M);
        partM[t * 4 + p] = M;
        partD[t * 4 + p] = D;
    }
    __syncthreads();
    if (tid < 40) {
        float M = partM[tid * 4];
        M = fmaxf(M, partM[tid * 4 + 1]); M = fmaxf(M, partM[tid * 4 + 2]); M = fmaxf(M, partM[tid * 4 + 3]);
        float D = 0.f;
#pragma unroll
        for (int p = 0; p < 4; ++p) D += partD[tid * 4 + p] * __expf(partM[tid * 4 + p] - M);
        sMX[tid] = M;
        sDI[tid] = rcpf_(D);
    }
    __syncthreads();

    for (int task = tid; task < 384; task += 256) {
        int s = task >> 3, c = task & 7;
        uint4 Hq, Lq;
        if (c >= 5) {
            Hq.x = Hq.y = Hq.z = Hq.w = 0u; Lq = Hq;
        } else {
            const float* srow = sm + s * 49 + c * 8;
            float wv[8];
#pragma unroll
            for (int jj = 0; jj < 8; ++jj) {
                int t = c * 8 + jj;
                wv[jj] = __expf(srow[jj] - sMX[t]) * sDI[t];
            }
            split2(wv[0], wv[1], Hq.x, Lq.x);
            split2(wv[2], wv[3], Hq.y, Lq.y);
            split2(wv[4], wv[5], Hq.z, Lq.z);
            split2(wv[6], wv[7], Hq.w, Lq.w);
        }
        int phys = c ^ (s & 7);
        *(uint4*)(smem + AT_SW + s * 128 + phys * 16) = Hq;
        *(uint4*)(smem + AT_SW_LO + s * 128 + phys * 16) = Lq;
    }
    __syncthreads();

    {
        uint4 aH[3][2], aL[3][2];
#pragma unroll
        for (int mt = 0; mt < 3; ++mt)
#pragma unroll
            for (int kk = 0; kk < 2; ++kk) {
                int s = mt * 16 + col;
                int phys = (kk * 4 + quad) ^ (s & 7);
                aH[mt][kk] = *(uint4*)(smem + AT_SW + s * 128 + phys * 16);
                aL[mt][kk] = *(uint4*)(smem + AT_SW_LO + s * 128 + phys * 16);
            }
        f4 acc[3][2];
#pragma unroll
        for (int mt = 0; mt < 3; ++mt) { acc[mt][0] = (f4){0,0,0,0}; acc[mt][1] = (f4){0,0,0,0}; }
#pragma unroll
        for (int which = 0; which < 2; ++which) {
            int nt = w + which * 4;
            int hrow = nt * 16 + col;
#pragma unroll
            for (int kk = 0; kk < 2; ++kk) {
                int phys = (kk * 4 + quad) ^ (hrow & 7);
                short8 bH = u4s8(*(uint4*)(smem + AT_SHCT + hrow * 128 + phys * 16));
                short8 bL = u4s8(*(uint4*)(smem + AT_SHCT_LO + hrow * 128 + phys * 16));
#pragma unroll
                for (int mt = 0; mt < 3; ++mt) {
                    short8 ah = u4s8(aH[mt][kk]), al = u4s8(aL[mt][kk]);
                    MFMA16(acc[mt][which], ah, bH);
                    MFMA16(acc[mt][which], ah, bL);
                    MFMA16(acc[mt][which], al, bH);
                }
            }
        }
        __syncthreads();
#pragma unroll
        for (int which = 0; which < 2; ++which) {
            int h = (w + which * 4) * 16 + col;
            int chunk = h >> 3, hb7 = (h & 7) * 2;
#pragma unroll
            for (int mt = 0; mt < 3; ++mt)
#pragma unroll
                for (int pr = 0; pr < 2; ++pr) {
                    unsigned Hp, Lp;
                    split2(acc[mt][which][pr * 2], acc[mt][which][pr * 2 + 1], Hp, Lp);
#pragma unroll
                    for (int k = 0; k < 2; ++k) {
                        int s = mt * 16 + quad * 4 + pr * 2 + k;
                        int phys = chunk ^ (s & 15);
                        *(unsigned short*)(smem + AT_SHA + s * 256 + phys * 16 + hb7) =
                            (unsigned short)(k ? (Hp >> 16) : Hp);
                        *(unsigned short*)(smem + AT_SHA_LO + s * 256 + phys * 16 + hb7) =
                            (unsigned short)(k ? (Lp >> 16) : Lp);
                    }
                }
        }
    }
    __syncthreads();

    {
        f4 acc[3][2];
#pragma unroll
        for (int mt = 0; mt < 3; ++mt) { acc[mt][0] = (f4){0,0,0,0}; acc[mt][1] = (f4){0,0,0,0}; }
#pragma unroll
        for (int kk = 0; kk < 4; ++kk)
#pragma unroll
            for (int mt = 0; mt < 3; ++mt) {
                int s = mt * 16 + col;
                int phys = (kk * 4 + quad) ^ (s & 15);
                short8 ah = u4s8(*(uint4*)(smem + AT_SHA + s * 256 + phys * 16));
                short8 al = u4s8(*(uint4*)(smem + AT_SHA_LO + s * 256 + phys * 16));
#pragma unroll
                for (int which = 0; which < 2; ++which) {
                    MFMA16(acc[mt][which], ah, u4s8(bw[which][kk][0]));
                    MFMA16(acc[mt][which], ah, u4s8(bw[which][kk][1]));
                    MFMA16(acc[mt][which], al, u4s8(bw[which][kk][0]));
                }
            }
        __syncthreads();
        int nts[2] = {ntc0, ntc1};
#pragma unroll
        for (int which = 0; which < 2; ++which) {
            int c = nts[which] * 16 + col;
#pragma unroll
            for (int mt = 0; mt < 3; ++mt)
#pragma unroll
                for (int r = 0; r < 4; ++r)
                    slog[(mt * 16 + quad * 4 + r) * 113 + c] = acc[mt][which][r] + bcv[which];
        }
    }
    __syncthreads();

    if (tid < 160) {
        int s = tid >> 2, p = tid & 3;
        int c0 = p * 26;
        int c1 = (c0 + 26 < CC) ? c0 + 26 : CC;
        const float* row = slog + s * 113;
        float M = row[c0];
        for (int c = c0 + 1; c < c1; ++c) M = fmaxf(M, row[c]);
        float D = 0.f;
        for (int c = c0; c < c1; ++c) D += __expf(row[c] - M);
        partM[s * 4 + p] = M;
        partD[s * 4 + p] = D;
    }
    __syncthreads();
    if (tid < 40) {
        float M = partM[tid * 4];
        M = fmaxf(M, partM[tid * 4 + 1]); M = fmaxf(M, partM[tid * 4 + 2]); M = fmaxf(M, partM[tid * 4 + 3]);
        float D = 0.f;
#pragma unroll
        for (int p = 0; p < 4; ++p) D += partD[tid * 4 + p] * __expf(partM[tid * 4 + p] - M);
        sMX[tid] = M;
        sDI[tid] = rcpf_(D);
    }
    __syncthreads();

    {
        int c = tid & 127, s0 = tid >> 7;
        if (c < CC) {
            float* ob = out + b * TT * CC;
            for (int s = s0; s < TT; s += 2)
                ob[s * CC + c] = __expf(slog[s * 113 + c] - sMX[s]) * sDI[s];
        }
    }
}

extern "C" void kernel_launch(void* const* d_in, const int* in_sizes, int n_in,
                              void* d_out, int out_size, void* d_ws, size_t ws_size,
                              hipStream_t stream) {
    const int*   ids   = (const int*)d_in[0];
    const float* emb_c = (const float*)d_in[1];
    const float* emb_a = (const float*)d_in[2];
    const float* W_ih  = (const float*)d_in[3];
    const float* W_hh  = (const float*)d_in[4];
    const float* b_ih  = (const float*)d_in[5];
    const float* b_hh  = (const float*)d_in[6];
    const float* W_cls = (const float*)d_in[7];
    const float* b_cls = (const float*)d_in[8];
    float* out = (float*)d_out;

    float* ha = (float*)d_ws;                               // [B][T][H] fp32
    float* hc = ha + (size_t)BB * TT * HH;                  // [B][T][H] fp32
    float* G  = hc + (size_t)BB * TT * HH;                  // [2][V][128][3] fp32 (pre-scaled)
    __hip_bfloat16* Whi = (__hip_bfloat16*)(G + (size_t)2 * VV * 384);
    __hip_bfloat16* Wlo = Whi + 384 * HH;
    unsigned short* WcH = (unsigned short*)(Wlo + 384 * HH);
    unsigned short* WcL = WcH + 112 * HH;
    unsigned short* WihH = WcL + 112 * HH;
    unsigned short* WihL = WihH + 384 * HH;

    prep_whh<<<(384 * HH + 255) / 256, 256, 0, stream>>>(W_hh, (unsigned short*)Whi, (unsigned short*)Wlo);
    prep_bf16split<<<(384 * HH + 255) / 256, 256, 0, stream>>>(W_ih, WihH, WihL, 384 * HH);
    prep_wcls<<<(112 * HH + 255) / 256, 256, 0, stream>>>(W_cls, WcH, WcL);
    prep_G_mfma<<<dim3((VV + 31) / 32, 2), 256, 0, stream>>>(emb_a, emb_c, WihH, WihL, b_ih, b_hh, G);
    gru_mfma<<<dim3(BB / 16 * 2), 512, 0, stream>>>(ids, G, Whi, Wlo, b_hh, ha, hc);
    attn_cls_mfma<<<BB, 256, 0, stream>>>(ha, hc, WcH, WcL, b_cls, out);
}

// Round 7
// 588.700 us; speedup vs baseline: 1.1235x; 1.1235x over previous
//
#include <hip/hip_runtime.h>
#include <hip/hip_bf16.h>

#define BB 8192
#define TT 40
#define HH 128
#define CC 102
#define VV 4450

#define L2E  1.4426950408889634f
#define L2E2 2.8853900817779268f

typedef __attribute__((ext_vector_type(8))) short short8;
typedef __attribute__((ext_vector_type(4))) float f4;

__device__ __forceinline__ float rcpf_(float x) { return __builtin_amdgcn_rcpf(x); }
__device__ __forceinline__ float exp2f_(float x) { return __builtin_amdgcn_exp2f(x); }

// LDS-only barrier: __syncthreads() forces s_waitcnt vmcnt(0) before s_barrier,
// draining global gathers/stores nobody reads cross-wave. The h-exchange only
// needs lgkmcnt(0) (ds_writes visible). Gathers keep flowing across the barrier
// and retire under the next step's MFMA phase (T4 counted-wait idiom).
__device__ __forceinline__ void barrier_lds() {
    asm volatile("s_waitcnt lgkmcnt(0)\n\ts_barrier" ::: "memory");
}

__device__ __forceinline__ unsigned short f2bf(float x) {
    union { float f; unsigned u; } v; v.f = x;
    unsigned r = v.u + 0x7FFFu + ((v.u >> 16) & 1u);
    return (unsigned short)(r >> 16);
}
__device__ __forceinline__ float bf2f(unsigned short h) {
    union { float f; unsigned u; } v; v.u = ((unsigned)h) << 16; return v.f;
}
__device__ __forceinline__ short8 u4s8(uint4 v) { return *(short8*)&v; }

// packed f32x2 -> bf16x2 (RNE), S0 -> low 16, S1 -> high 16
__device__ __forceinline__ unsigned cvtpk_bf16(float lo, float hi) {
    unsigned r;
    asm("v_cvt_pk_bf16_f32 %0, %1, %2" : "=v"(r) : "v"(lo), "v"(hi));
    return r;
}
// hi/lo split of two floats: H = packed bf16 hi parts, L = packed bf16 residuals
__device__ __forceinline__ void split2(float a, float b, unsigned& H, unsigned& L) {
    H = cvtpk_bf16(a, b);
    float ra = __uint_as_float(H << 16);
    float rb = __uint_as_float(H & 0xFFFF0000u);
    L = cvtpk_bf16(a - ra, b - rb);
}

struct __attribute__((aligned(4))) G3 { float r, z, n; };

#define MFMA16(acc, a, b) acc = __builtin_amdgcn_mfma_f32_16x16x32_bf16(a, b, acc, 0, 0, 0)

// ---------- prep 1: split fp32 array into bf16 hi/lo (unscaled, for W_ih) ----------
__global__ __launch_bounds__(256) void prep_bf16split(const float* __restrict__ W,
                                                      unsigned short* __restrict__ hi,
                                                      unsigned short* __restrict__ lo, int n) {
    int i = blockIdx.x * 256 + threadIdx.x;
    if (i < n) {
        float x = W[i];
        unsigned short h = f2bf(x);
        hi[i] = h;
        lo[i] = f2bf(x - bf2f(h));
    }
}

// ---------- prep 1a: split W_hh with per-gate exp2 pre-scale ----------
// rows [0,256) (r,z gates): * log2e  -> sigmoid via exp2
// rows [256,384) (n gate) : * 2*log2e -> tanh via exp2
__global__ __launch_bounds__(256) void prep_whh(const float* __restrict__ W,
                                                unsigned short* __restrict__ hi,
                                                unsigned short* __restrict__ lo) {
    int i = blockIdx.x * 256 + threadIdx.x;
    if (i < 384 * HH) {
        float s = (i < 256 * HH) ? L2E : L2E2;
        float x = W[i] * s;
        unsigned short h = f2bf(x);
        hi[i] = h;
        lo[i] = f2bf(x - bf2f(h));
    }
}

// ---------- prep 1b: split W_cls into bf16 hi/lo, padded to 112 rows ----------
__global__ __launch_bounds__(256) void prep_wcls(const float* __restrict__ W,
                                                 unsigned short* __restrict__ hi,
                                                 unsigned short* __restrict__ lo) {
    int i = blockIdx.x * 256 + threadIdx.x;
    if (i < 112 * HH) {
        int r = i >> 7;
        float x = (r < CC) ? W[i] : 0.f;
        unsigned short h = f2bf(x);
        hi[i] = h;
        lo[i] = f2bf(x - bf2f(h));
    }
}

// ---------- prep 2: G[src][v][j][gate] = (emb[v] @ W_ih^T + biases) * gate_scale ----------
// Output layout: G[v*384 + j*3 + g]  (j = hidden col 0..127, g = gate r/z/n)
__global__ __launch_bounds__(256) void prep_G_mfma(
    const float* __restrict__ emb_a, const float* __restrict__ emb_c,
    const unsigned short* __restrict__ WihH, const unsigned short* __restrict__ WihL,
    const float* __restrict__ b_ih, const float* __restrict__ b_hh,
    float* __restrict__ G)
{
    __shared__ uint4 se[2][32][16];   // [hi/lo][row][swizzled 16B k-chunk]

    const int tid = threadIdx.x;
    const int src = blockIdx.y;
    const float* emb = src ? emb_c : emb_a;
    const int v0 = blockIdx.x * 32;

    const int lane = tid & 63;
    const int w = tid >> 6;
    const int mcol = lane & 15;
    const int quad = lane >> 4;

    // stage emb tile -> bf16 hi/lo (xor-swizzled: phys chunk = chunk ^ (row&15))
#pragma unroll
    for (int i = 0; i < 4; ++i) {
        int task = tid + 256 * i;       // 0..1023 = 32 rows x 32 float4
        int row = task >> 5, q = task & 31;
        int v = v0 + row;
        float4 x = make_float4(0.f, 0.f, 0.f, 0.f);
        if (v < VV) x = ((const float4*)(emb + (size_t)v * HH))[q];
        uint2 Hw, Lw;
        split2(x.x, x.y, Hw.x, Lw.x);
        split2(x.z, x.w, Hw.y, Lw.y);
        int phys = (q >> 1) ^ (row & 15);
        ((uint2*)&se[0][row][phys])[q & 1] = Hw;
        ((uint2*)&se[1][row][phys])[q & 1] = Lw;
    }

    // per-lane biases for the 6 output col groups
    float bias[6];
#pragma unroll
    for (int n6 = 0; n6 < 6; ++n6) {
        int c = w * 96 + n6 * 16 + mcol;
        bias[n6] = b_ih[c] + (c < 256 ? b_hh[c] : 0.f);
    }

    f4 acc[2][6];
#pragma unroll
    for (int mt = 0; mt < 2; ++mt)
#pragma unroll
        for (int n6 = 0; n6 < 6; ++n6) acc[mt][n6] = (f4){0.f, 0.f, 0.f, 0.f};

    __syncthreads();

#pragma unroll
    for (int kk = 0; kk < 4; ++kk) {
        uint4 bH[6], bL[6];
#pragma unroll
        for (int n6 = 0; n6 < 6; ++n6) {
            int rowc = w * 96 + n6 * 16 + mcol;
            bH[n6] = *((const uint4*)WihH + rowc * 16 + kk * 4 + quad);
            bL[n6] = *((const uint4*)WihL + rowc * 16 + kk * 4 + quad);
        }
#pragma unroll
        for (int mt = 0; mt < 2; ++mt) {
            int m = mt * 16 + mcol;
            int phys = (kk * 4 + quad) ^ mcol;
            short8 ah = u4s8(se[0][m][phys]);
            short8 al = u4s8(se[1][m][phys]);
#pragma unroll
            for (int n6 = 0; n6 < 6; ++n6) {
                MFMA16(acc[mt][n6], ah, u4s8(bH[n6]));
                MFMA16(acc[mt][n6], ah, u4s8(bL[n6]));
                MFMA16(acc[mt][n6], al, u4s8(bH[n6]));
            }
        }
    }

    float* gout = G + (size_t)src * VV * 384;
#pragma unroll
    for (int mt = 0; mt < 2; ++mt)
#pragma unroll
        for (int r = 0; r < 4; ++r) {
            int m = mt * 16 + quad * 4 + r;
            int v = v0 + m;
            if (v < VV) {
#pragma unroll
                for (int n6 = 0; n6 < 6; ++n6) {
                    int c = w * 96 + n6 * 16 + mcol;
                    int g = c >> 7, jj = c & 127;
                    float scl = (g < 2) ? L2E : L2E2;
                    gout[(size_t)v * 384 + jj * 3 + g] = (acc[mt][n6][r] + bias[n6]) * scl;
                }
            }
        }
}

// ---------- main GRU: R5 structure (best verified, 256 us) + lgkm-only barrier ----------
// Tile-shape search is closed: M=64-fused (R4: 337us, gather-set blowup) and
// M=16 (R6: 316us, fixed per-step cost dominates) both lose to M=32 (256us).
// R7 change: the 40 in-loop __syncthreads() each forced vmcnt(0) -> exposed
// ~full gather latency per step. barrier_lds() waits lgkmcnt only (the actual
// cross-wave dependency: ds_writes of the h-exchange).
// __launch_bounds__(512, 2): 108 VGPR, no spill (R1: (512,4) forced 64 + spill).
__global__ __launch_bounds__(512, 2) void gru_mfma(
    const int* __restrict__ ids, const float* __restrict__ G,
    const __hip_bfloat16* __restrict__ Whi, const __hip_bfloat16* __restrict__ Wlo,
    const float* __restrict__ b_hh, float* __restrict__ ha, float* __restrict__ hc)
{
    __shared__ uint4 sh[2][2][32][16];
    __shared__ int sids[32 * TT];

    const int tid = threadIdx.x;
    const int src = blockIdx.x & 1;          // XCD parity = src parity
    const int b0 = (blockIdx.x >> 1) * 32;
    const float* Gs = G + (size_t)src * VV * 384;
    float* hout = src ? hc : ha;

    const int lane = tid & 63;
    const int w = tid >> 6;
    const int nc0 = w * 16;
    const int mcol = lane & 15;
    const int quad = lane >> 4;

    for (int idx = tid; idx < 32 * TT; idx += 512)
        sids[idx] = ids[b0 * TT + idx];

    {
        uint4 z; z.x = z.y = z.z = z.w = 0u;
        uint4* p = &sh[0][0][0][0];
        for (int idx = tid; idx < 2 * 32 * 16; idx += 512) p[idx] = z;
    }

    short8 bh[3][4], bl[3][4];
#pragma unroll
    for (int g = 0; g < 3; ++g)
#pragma unroll
        for (int kk = 0; kk < 4; ++kk) {
            int row = g * 128 + nc0 + mcol;
            uint4 vh = *((const uint4*)Whi + row * 16 + kk * 4 + quad);
            uint4 vl = *((const uint4*)Wlo + row * 16 + kk * 4 + quad);
            bh[g][kk] = u4s8(vh);
            bl[g][kk] = u4s8(vl);
        }

    const int j = nc0 + mcol;
    const float bhn = L2E2 * b_hh[256 + j];
    const float* gbase = Gs + 3 * j;

    f4 hreg[2];
    hreg[0] = (f4){0.f, 0.f, 0.f, 0.f};
    hreg[1] = (f4){0.f, 0.f, 0.f, 0.f};

    __syncthreads();

    G3 gc[2][4];
#pragma unroll
    for (int mt = 0; mt < 2; ++mt)
#pragma unroll
        for (int reg = 0; reg < 4; ++reg) {
            int m = mt * 16 + quad * 4 + reg;
            int id = sids[m * TT + 0];
            gc[mt][reg] = *(const G3*)(gbase + (size_t)id * 384);
        }

    const int s_slot = j >> 3;
    const int jb = j & 7;

    int buf = 0;
#pragma unroll 1
    for (int t = 0; t < TT; ++t) {
        f4 acc[3][2];
#pragma unroll
        for (int g = 0; g < 3; ++g)
#pragma unroll
            for (int mt = 0; mt < 2; ++mt) acc[g][mt] = (f4){0.f, 0.f, 0.f, 0.f};

#pragma unroll
        for (int mt = 0; mt < 2; ++mt)
#pragma unroll
            for (int kk = 0; kk < 4; ++kk) {
                int m = mt * 16 + mcol;
                int phys = (kk * 4 + quad) ^ mcol;
                uint4 avh = sh[buf][0][m][phys];
                uint4 avl = sh[buf][1][m][phys];
                short8 ah = u4s8(avh), al = u4s8(avl);
#pragma unroll
                for (int g = 0; g < 3; ++g) {
                    MFMA16(acc[g][mt], ah, bh[g][kk]);
                    MFMA16(acc[g][mt], ah, bl[g][kk]);
                    MFMA16(acc[g][mt], al, bh[g][kk]);
                }
            }

        const int nbuf = buf ^ 1;
#pragma unroll
        for (int mt = 0; mt < 2; ++mt) {
            float hv4[4];
#pragma unroll
            for (int reg = 0; reg < 4; ++reg) {
                G3 g = gc[mt][reg];
                // inputs pre-scaled by log2e (r,z) / 2*log2e (n) -> raw exp2
                float rr = rcpf_(1.f + exp2f_(-(acc[0][mt][reg] + g.r)));
                float zz = rcpf_(1.f + exp2f_(-(acc[1][mt][reg] + g.z)));
                float y  = g.n + rr * (acc[2][mt][reg] + bhn);
                float nn = 1.f - 2.f * rcpf_(exp2f_(y) + 1.f);
                float hv = fmaf(zz, hreg[mt][reg] - nn, nn);
                hreg[mt][reg] = hv;
                hv4[reg] = hv;

                int m = mt * 16 + quad * 4 + reg;
                hout[((size_t)(b0 + m) * TT + t) * HH + j] = hv;
            }
#pragma unroll
            for (int pr = 0; pr < 2; ++pr) {
                unsigned Hp, Lp;
                split2(hv4[pr * 2], hv4[pr * 2 + 1], Hp, Lp);
#pragma unroll
                for (int k = 0; k < 2; ++k) {
                    int m = mt * 16 + quad * 4 + pr * 2 + k;
                    int phys = s_slot ^ (m & 15);
                    unsigned short hb = (unsigned short)(k ? (Hp >> 16) : Hp);
                    unsigned short lb = (unsigned short)(k ? (Lp >> 16) : Lp);
                    ((unsigned short*)&sh[nbuf][0][m][phys])[jb] = hb;
                    ((unsigned short*)&sh[nbuf][1][m][phys])[jb] = lb;
                }
            }
        }

        if (t < TT - 1) {
#pragma unroll
            for (int mt = 0; mt < 2; ++mt)
#pragma unroll
                for (int reg = 0; reg < 4; ++reg) {
                    int m = mt * 16 + quad * 4 + reg;
                    int id = sids[m * TT + t + 1];
                    gc[mt][reg] = *(const G3*)(gbase + (size_t)id * 384);
                }
        }
        barrier_lds();   // lgkm-only: gathers/stores stay in flight across it
        buf ^= 1;
    }
}

// ---------- attention + classifier, MFMA version ----------
#define AT_SHA     0
#define AT_SHA_LO  12288
#define AT_SHCT    24576
#define AT_SHCT_LO 40960
#define AT_SM      57344
#define AT_SW      66752
#define AT_SW_LO   72896
#define AT_PARTM   79040
#define AT_PARTD   79808
#define AT_SMX     80576
#define AT_SDI     80768
#define AT_TOTAL   80960

__global__ __launch_bounds__(256, 2) void attn_cls_mfma(
    const float* __restrict__ ha, const float* __restrict__ hc,
    const unsigned short* __restrict__ WcH, const unsigned short* __restrict__ WcL,
    const float* __restrict__ b_cls, float* __restrict__ out)
{
    __shared__ __attribute__((aligned(16))) char smem[AT_TOTAL];
    const int tid = threadIdx.x;
    const int lane = tid & 63;
    const int w = tid >> 6;
    const int quad = lane >> 4;
    const int col = lane & 15;
    const size_t b = blockIdx.x;

    float* sm    = (float*)(smem + AT_SM);
    float* slog  = (float*)(smem + AT_SM);
    float* partM = (float*)(smem + AT_PARTM);
    float* partD = (float*)(smem + AT_PARTD);
    float* sMX   = (float*)(smem + AT_SMX);
    float* sDI   = (float*)(smem + AT_SDI);

    const int ntc0 = (w < 3) ? w : 3;
    const int ntc1 = (w < 3) ? w + 4 : 3;
    uint4 bw[2][4][2];
    float bcv[2];
    {
        int nts[2] = {ntc0, ntc1};
#pragma unroll
        for (int which = 0; which < 2; ++which) {
            int row = nts[which] * 16 + col;
#pragma unroll
            for (int kk = 0; kk < 4; ++kk) {
                bw[which][kk][0] = *((const uint4*)WcH + row * 16 + kk * 4 + quad);
                bw[which][kk][1] = *((const uint4*)WcL + row * 16 + kk * 4 + quad);
            }
            bcv[which] = (row < CC) ? b_cls[row] : 0.f;
        }
    }

    {
        const float4* hab = (const float4*)(ha + b * TT * HH);
#pragma unroll
        for (int i = 0; i < 5; ++i) {
            int f4i = tid + 256 * i;
            int row = f4i >> 5, q = f4i & 31;
            float4 v = hab[f4i];
            uint2 Hw, Lw;
            split2(v.x, v.y, Hw.x, Lw.x);
            split2(v.z, v.w, Hw.y, Lw.y);
            int phys = (q >> 1) ^ (row & 15);
            int off = row * 256 + phys * 16 + (q & 1) * 8;
            *(uint2*)(smem + AT_SHA + off) = Hw;
            *(uint2*)(smem + AT_SHA_LO + off) = Lw;
        }
        if (tid < 128) {
            int row = 40 + (tid >> 4), c = tid & 15;
            uint4 z; z.x = z.y = z.z = z.w = 0u;
            *(uint4*)(smem + AT_SHA + row * 256 + c * 16) = z;
            *(uint4*)(smem + AT_SHA_LO + row * 256 + c * 16) = z;
        }
        const float* hcb = hc + b * TT * HH;
        for (int task = tid; task < 640; task += 256) {
            int h = task & 127, c = task >> 7;
            float x[8];
#pragma unroll
            for (int jj = 0; jj < 8; ++jj) x[jj] = hcb[(c * 8 + jj) * HH + h];
            uint4 Hq, Lq;
            split2(x[0], x[1], Hq.x, Lq.x);
            split2(x[2], x[3], Hq.y, Lq.y);
            split2(x[4], x[5], Hq.z, Lq.z);
            split2(x[6], x[7], Hq.w, Lq.w);
            int phys = c ^ (h & 7);
            *(uint4*)(smem + AT_SHCT + h * 128 + phys * 16) = Hq;
            *(uint4*)(smem + AT_SHCT_LO + h * 128 + phys * 16) = Lq;
        }
        for (int task = tid; task < 384; task += 256) {
            int h = task & 127, c = 5 + (task >> 7);
            int phys = c ^ (h & 7);
            uint4 z; z.x = z.y = z.z = z.w = 0u;
            *(uint4*)(smem + AT_SHCT + h * 128 + phys * 16) = z;
            *(uint4*)(smem + AT_SHCT_LO + h * 128 + phys * 16) = z;
        }
    }
    __syncthreads();

    if (w < 3) {
        const int mt = w;
        uint4 aH[4], aL[4];
#pragma unroll
        for (int kk = 0; kk < 4; ++kk) {
            int phys = (kk * 4 + quad) ^ col;
            int off = (mt * 16 + col) * 256 + phys * 16;
            aH[kk] = *(uint4*)(smem + AT_SHA + off);
            aL[kk] = *(uint4*)(smem + AT_SHA_LO + off);
        }
        f4 acc[3];
#pragma unroll
        for (int nt = 0; nt < 3; ++nt) acc[nt] = (f4){0.f, 0.f, 0.f, 0.f};
#pragma unroll
        for (int kk = 0; kk < 4; ++kk) {
            short8 ah = u4s8(aH[kk]), al = u4s8(aL[kk]);
#pragma unroll
            for (int nt = 0; nt < 3; ++nt) {
                int phys = (kk * 4 + quad) ^ col;
                int off = (nt * 16 + col) * 256 + phys * 16;
                short8 bH = u4s8(*(uint4*)(smem + AT_SHA + off));
                short8 bL = u4s8(*(uint4*)(smem + AT_SHA_LO + off));
                MFMA16(acc[nt], ah, bH);
                MFMA16(acc[nt], ah, bL);
                MFMA16(acc[nt], al, bH);
            }
        }
#pragma unroll
        for (int nt = 0; nt < 3; ++nt)
#pragma unroll
            for (int r = 0; r < 4; ++r)
                sm[(mt * 16 + quad * 4 + r) * 49 + nt * 16 + col] = acc[nt][r];
    }
    __syncthreads();

    if (tid < 160) {
        int t = tid >> 2, p = tid & 3;
        const float* row = sm + t * 49 + p * 10;
        float M = row[0];
#pragma unroll
        for (int i = 1; i < 10; ++i) M = fmaxf(M, row[i]);
        float D = 0.f;
#pragma unroll
        for (int i = 0; i < 10; ++i) D += __expf(row[i] - M);
        partM[t * 4 + p] = M;
        partD[t * 4 + p] = D;
    }
    __syncthreads();
    if (tid < 40) {
        float M = partM[tid * 4];
        M = fmaxf(M, partM[tid * 4 + 1]); M = fmaxf(M, partM[tid * 4 + 2]); M = fmaxf(M, partM[tid * 4 + 3]);
        float D = 0.f;
#pragma unroll
        for (int p = 0; p < 4; ++p) D += partD[tid * 4 + p] * __expf(partM[tid * 4 + p] - M);
        sMX[tid] = M;
        sDI[tid] = rcpf_(D);
    }
    __syncthreads();

    for (int task = tid; task < 384; task += 256) {
        int s = task >> 3, c = task & 7;
        uint4 Hq, Lq;
        if (c >= 5) {
            Hq.x = Hq.y = Hq.z = Hq.w = 0u; Lq = Hq;
        } else {
            const float* srow = sm + s * 49 + c * 8;
            float wv[8];
#pragma unroll
            for (int jj = 0; jj < 8; ++jj) {
                int t = c * 8 + jj;
                wv[jj] = __expf(srow[jj] - sMX[t]) * sDI[t];
            }
            split2(wv[0], wv[1], Hq.x, Lq.x);
            split2(wv[2], wv[3], Hq.y, Lq.y);
            split2(wv[4], wv[5], Hq.z, Lq.z);
            split2(wv[6], wv[7], Hq.w, Lq.w);
        }
        int phys = c ^ (s & 7);
        *(uint4*)(smem + AT_SW + s * 128 + phys * 16) = Hq;
        *(uint4*)(smem + AT_SW_LO + s * 128 + phys * 16) = Lq;
    }
    __syncthreads();

    {
        uint4 aH[3][2], aL[3][2];
#pragma unroll
        for (int mt = 0; mt < 3; ++mt)
#pragma unroll
            for (int kk = 0; kk < 2; ++kk) {
                int s = mt * 16 + col;
                int phys = (kk * 4 + quad) ^ (s & 7);
                aH[mt][kk] = *(uint4*)(smem + AT_SW + s * 128 + phys * 16);
                aL[mt][kk] = *(uint4*)(smem + AT_SW_LO + s * 128 + phys * 16);
            }
        f4 acc[3][2];
#pragma unroll
        for (int mt = 0; mt < 3; ++mt) { acc[mt][0] = (f4){0,0,0,0}; acc[mt][1] = (f4){0,0,0,0}; }
#pragma unroll
        for (int which = 0; which < 2; ++which) {
            int nt = w + which * 4;
            int hrow = nt * 16 + col;
#pragma unroll
            for (int kk = 0; kk < 2; ++kk) {
                int phys = (kk * 4 + quad) ^ (hrow & 7);
                short8 bH = u4s8(*(uint4*)(smem + AT_SHCT + hrow * 128 + phys * 16));
                short8 bL = u4s8(*(uint4*)(smem + AT_SHCT_LO + hrow * 128 + phys * 16));
#pragma unroll
                for (int mt = 0; mt < 3; ++mt) {
                    short8 ah = u4s8(aH[mt][kk]), al = u4s8(aL[mt][kk]);
                    MFMA16(acc[mt][which], ah, bH);
                    MFMA16(acc[mt][which], ah, bL);
                    MFMA16(acc[mt][which], al, bH);
                }
            }
        }
        __syncthreads();
#pragma unroll
        for (int which = 0; which < 2; ++which) {
            int h = (w + which * 4) * 16 + col;
            int chunk = h >> 3, hb7 = (h & 7) * 2;
#pragma unroll
            for (int mt = 0; mt < 3; ++mt)
#pragma unroll
                for (int pr = 0; pr < 2; ++pr) {
                    unsigned Hp, Lp;
                    split2(acc[mt][which][pr * 2], acc[mt][which][pr * 2 + 1], Hp, Lp);
#pragma unroll
                    for (int k = 0; k < 2; ++k) {
                        int s = mt * 16 + quad * 4 + pr * 2 + k;
                        int phys = chunk ^ (s & 15);
                        *(unsigned short*)(smem + AT_SHA + s * 256 + phys * 16 + hb7) =
                            (unsigned short)(k ? (Hp >> 16) : Hp);
                        *(unsigned short*)(smem + AT_SHA_LO + s * 256 + phys * 16 + hb7) =
                            (unsigned short)(k ? (Lp >> 16) : Lp);
                    }
                }
        }
    }
    __syncthreads();

    {
        f4 acc[3][2];
#pragma unroll
        for (int mt = 0; mt < 3; ++mt) { acc[mt][0] = (f4){0,0,0,0}; acc[mt][1] = (f4){0,0,0,0}; }
#pragma unroll
        for (int kk = 0; kk < 4; ++kk)
#pragma unroll
            for (int mt = 0; mt < 3; ++mt) {
                int s = mt * 16 + col;
                int phys = (kk * 4 + quad) ^ (s & 15);
                short8 ah = u4s8(*(uint4*)(smem + AT_SHA + s * 256 + phys * 16));
                short8 al = u4s8(*(uint4*)(smem + AT_SHA_LO + s * 256 + phys * 16));
#pragma unroll
                for (int which = 0; which < 2; ++which) {
                    MFMA16(acc[mt][which], ah, u4s8(bw[which][kk][0]));
                    MFMA16(acc[mt][which], ah, u4s8(bw[which][kk][1]));
                    MFMA16(acc[mt][which], al, u4s8(bw[which][kk][0]));
                }
            }
        __syncthreads();
        int nts[2] = {ntc0, ntc1};
#pragma unroll
        for (int which = 0; which < 2; ++which) {
            int c = nts[which] * 16 + col;
#pragma unroll
            for (int mt = 0; mt < 3; ++mt)
#pragma unroll
                for (int r = 0; r < 4; ++r)
                    slog[(mt * 16 + quad * 4 + r) * 113 + c] = acc[mt][which][r] + bcv[which];
        }
    }
    __syncthreads();

    if (tid < 160) {
        int s = tid >> 2, p = tid & 3;
        int c0 = p * 26;
        int c1 = (c0 + 26 < CC) ? c0 + 26 : CC;
        const float* row = slog + s * 113;
        float M = row[c0];
        for (int c = c0 + 1; c < c1; ++c) M = fmaxf(M, row[c]);
        float D = 0.f;
        for (int c = c0; c < c1; ++c) D += __expf(row[c] - M);
        partM[s * 4 + p] = M;
        partD[s * 4 + p] = D;
    }
    __syncthreads();
    if (tid < 40) {
        float M = partM[tid * 4];
        M = fmaxf(M, partM[tid * 4 + 1]); M = fmaxf(M, partM[tid * 4 + 2]); M = fmaxf(M, partM[tid * 4 + 3]);
        float D = 0.f;
#pragma unroll
        for (int p = 0; p < 4; ++p) D += partD[tid * 4 + p] * __expf(partM[tid * 4 + p] - M);
        sMX[tid] = M;
        sDI[tid] = rcpf_(D);
    }
    __syncthreads();

    {
        int c = tid & 127, s0 = tid >> 7;
        if (c < CC) {
            float* ob = out + b * TT * CC;
            for (int s = s0; s < TT; s += 2)
                ob[s * CC + c] = __expf(slog[s * 113 + c] - sMX[s]) * sDI[s];
        }
    }
}

extern "C" void kernel_launch(void* const* d_in, const int* in_sizes, int n_in,
                              void* d_out, int out_size, void* d_ws, size_t ws_size,
                              hipStream_t stream) {
    const int*   ids   = (const int*)d_in[0];
    const float* emb_c = (const float*)d_in[1];
    const float* emb_a = (const float*)d_in[2];
    const float* W_ih  = (const float*)d_in[3];
    const float* W_hh  = (const float*)d_in[4];
    const float* b_ih  = (const float*)d_in[5];
    const float* b_hh  = (const float*)d_in[6];
    const float* W_cls = (const float*)d_in[7];
    const float* b_cls = (const float*)d_in[8];
    float* out = (float*)d_out;

    float* ha = (float*)d_ws;                               // [B][T][H] fp32
    float* hc = ha + (size_t)BB * TT * HH;                  // [B][T][H] fp32
    float* G  = hc + (size_t)BB * TT * HH;                  // [2][V][128][3] fp32 (pre-scaled)
    __hip_bfloat16* Whi = (__hip_bfloat16*)(G + (size_t)2 * VV * 384);
    __hip_bfloat16* Wlo = Whi + 384 * HH;
    unsigned short* WcH = (unsigned short*)(Wlo + 384 * HH);
    unsigned short* WcL = WcH + 112 * HH;
    unsigned short* WihH = WcL + 112 * HH;
    unsigned short* WihL = WihH + 384 * HH;

    prep_whh<<<(384 * HH + 255) / 256, 256, 0, stream>>>(W_hh, (unsigned short*)Whi, (unsigned short*)Wlo);
    prep_bf16split<<<(384 * HH + 255) / 256, 256, 0, stream>>>(W_ih, WihH, WihL, 384 * HH);
    prep_wcls<<<(112 * HH + 255) / 256, 256, 0, stream>>>(W_cls, WcH, WcL);
    prep_G_mfma<<<dim3((VV + 31) / 32, 2), 256, 0, stream>>>(emb_a, emb_c, WihH, WihL, b_ih, b_hh, G);
    gru_mfma<<<dim3(BB / 32 * 2), 512, 0, stream>>>(ids, G, Whi, Wlo, b_hh, ha, hc);
    attn_cls_mfma<<<BB, 256, 0, stream>>>(ha, hc, WcH, WcL, b_cls, out);
}

// Round 8
// 549.314 us; speedup vs baseline: 1.2040x; 1.0717x over previous
//
#include <hip/hip_runtime.h>
#include <hip/hip_bf16.h>

#define BB 8192
#define TT 40
#define HH 128
#define CC 102
#define VV 4450

#define L2E  1.4426950408889634f
#define L2E2 2.8853900817779268f

typedef __attribute__((ext_vector_type(8))) short short8;
typedef __attribute__((ext_vector_type(4))) float f4;

__device__ __forceinline__ float rcpf_(float x) { return __builtin_amdgcn_rcpf(x); }
__device__ __forceinline__ float exp2f_(float x) { return __builtin_amdgcn_exp2f(x); }

// LDS-only barrier: skips the vmcnt(0) drain __syncthreads() forces (R7: +1.5%).
__device__ __forceinline__ void barrier_lds() {
    asm volatile("s_waitcnt lgkmcnt(0)\n\ts_barrier" ::: "memory");
}

__device__ __forceinline__ unsigned short f2bf(float x) {
    union { float f; unsigned u; } v; v.f = x;
    unsigned r = v.u + 0x7FFFu + ((v.u >> 16) & 1u);
    return (unsigned short)(r >> 16);
}
__device__ __forceinline__ float bf2f(unsigned short h) {
    union { float f; unsigned u; } v; v.u = ((unsigned)h) << 16; return v.f;
}
__device__ __forceinline__ short8 u4s8(uint4 v) { return *(short8*)&v; }

// packed f32x2 -> bf16x2 (RNE), S0 -> low 16, S1 -> high 16
__device__ __forceinline__ unsigned cvtpk_bf16(float lo, float hi) {
    unsigned r;
    asm("v_cvt_pk_bf16_f32 %0, %1, %2" : "=v"(r) : "v"(lo), "v"(hi));
    return r;
}
// hi/lo split of two floats: H = packed bf16 hi parts, L = packed bf16 residuals
__device__ __forceinline__ void split2(float a, float b, unsigned& H, unsigned& L) {
    H = cvtpk_bf16(a, b);
    float ra = __uint_as_float(H << 16);
    float rb = __uint_as_float(H & 0xFFFF0000u);
    L = cvtpk_bf16(a - ra, b - rb);
}

struct __attribute__((aligned(4))) G3 { float r, z, n; };

#define MFMA16(acc, a, b) acc = __builtin_amdgcn_mfma_f32_16x16x32_bf16(a, b, acc, 0, 0, 0)

// ---------- prep 1: split fp32 array into bf16 hi/lo (unscaled, for W_ih) ----------
__global__ __launch_bounds__(256) void prep_bf16split(const float* __restrict__ W,
                                                      unsigned short* __restrict__ hi,
                                                      unsigned short* __restrict__ lo, int n) {
    int i = blockIdx.x * 256 + threadIdx.x;
    if (i < n) {
        float x = W[i];
        unsigned short h = f2bf(x);
        hi[i] = h;
        lo[i] = f2bf(x - bf2f(h));
    }
}

// ---------- prep 1a: split W_hh with per-gate exp2 pre-scale ----------
__global__ __launch_bounds__(256) void prep_whh(const float* __restrict__ W,
                                                unsigned short* __restrict__ hi,
                                                unsigned short* __restrict__ lo) {
    int i = blockIdx.x * 256 + threadIdx.x;
    if (i < 384 * HH) {
        float s = (i < 256 * HH) ? L2E : L2E2;
        float x = W[i] * s;
        unsigned short h = f2bf(x);
        hi[i] = h;
        lo[i] = f2bf(x - bf2f(h));
    }
}

// ---------- prep 1b: split W_cls into bf16 hi/lo, padded to 112 rows ----------
__global__ __launch_bounds__(256) void prep_wcls(const float* __restrict__ W,
                                                 unsigned short* __restrict__ hi,
                                                 unsigned short* __restrict__ lo) {
    int i = blockIdx.x * 256 + threadIdx.x;
    if (i < 112 * HH) {
        int r = i >> 7;
        float x = (r < CC) ? W[i] : 0.f;
        unsigned short h = f2bf(x);
        hi[i] = h;
        lo[i] = f2bf(x - bf2f(h));
    }
}

// ---------- prep 2: G[src][v][j][gate] = (emb[v] @ W_ih^T + biases) * gate_scale ----------
__global__ __launch_bounds__(256) void prep_G_mfma(
    const float* __restrict__ emb_a, const float* __restrict__ emb_c,
    const unsigned short* __restrict__ WihH, const unsigned short* __restrict__ WihL,
    const float* __restrict__ b_ih, const float* __restrict__ b_hh,
    float* __restrict__ G)
{
    __shared__ uint4 se[2][32][16];

    const int tid = threadIdx.x;
    const int src = blockIdx.y;
    const float* emb = src ? emb_c : emb_a;
    const int v0 = blockIdx.x * 32;

    const int lane = tid & 63;
    const int w = tid >> 6;
    const int mcol = lane & 15;
    const int quad = lane >> 4;

#pragma unroll
    for (int i = 0; i < 4; ++i) {
        int task = tid + 256 * i;
        int row = task >> 5, q = task & 31;
        int v = v0 + row;
        float4 x = make_float4(0.f, 0.f, 0.f, 0.f);
        if (v < VV) x = ((const float4*)(emb + (size_t)v * HH))[q];
        uint2 Hw, Lw;
        split2(x.x, x.y, Hw.x, Lw.x);
        split2(x.z, x.w, Hw.y, Lw.y);
        int phys = (q >> 1) ^ (row & 15);
        ((uint2*)&se[0][row][phys])[q & 1] = Hw;
        ((uint2*)&se[1][row][phys])[q & 1] = Lw;
    }

    float bias[6];
#pragma unroll
    for (int n6 = 0; n6 < 6; ++n6) {
        int c = w * 96 + n6 * 16 + mcol;
        bias[n6] = b_ih[c] + (c < 256 ? b_hh[c] : 0.f);
    }

    f4 acc[2][6];
#pragma unroll
    for (int mt = 0; mt < 2; ++mt)
#pragma unroll
        for (int n6 = 0; n6 < 6; ++n6) acc[mt][n6] = (f4){0.f, 0.f, 0.f, 0.f};

    __syncthreads();

#pragma unroll
    for (int kk = 0; kk < 4; ++kk) {
        uint4 bH[6], bL[6];
#pragma unroll
        for (int n6 = 0; n6 < 6; ++n6) {
            int rowc = w * 96 + n6 * 16 + mcol;
            bH[n6] = *((const uint4*)WihH + rowc * 16 + kk * 4 + quad);
            bL[n6] = *((const uint4*)WihL + rowc * 16 + kk * 4 + quad);
        }
#pragma unroll
        for (int mt = 0; mt < 2; ++mt) {
            int m = mt * 16 + mcol;
            int phys = (kk * 4 + quad) ^ mcol;
            short8 ah = u4s8(se[0][m][phys]);
            short8 al = u4s8(se[1][m][phys]);
#pragma unroll
            for (int n6 = 0; n6 < 6; ++n6) {
                MFMA16(acc[mt][n6], ah, u4s8(bH[n6]));
                MFMA16(acc[mt][n6], ah, u4s8(bL[n6]));
                MFMA16(acc[mt][n6], al, u4s8(bH[n6]));
            }
        }
    }

    float* gout = G + (size_t)src * VV * 384;
#pragma unroll
    for (int mt = 0; mt < 2; ++mt)
#pragma unroll
        for (int r = 0; r < 4; ++r) {
            int m = mt * 16 + quad * 4 + r;
            int v = v0 + m;
            if (v < VV) {
#pragma unroll
                for (int n6 = 0; n6 < 6; ++n6) {
                    int c = w * 96 + n6 * 16 + mcol;
                    int g = c >> 7, jj = c & 127;
                    float scl = (g < 2) ? L2E : L2E2;
                    gout[(size_t)v * 384 + jj * 3 + g] = (acc[mt][n6][r] + bias[n6]) * scl;
                }
            }
        }
}

// ---------- main GRU: R7 (best verified, 252.5 us) — unchanged ----------
__global__ __launch_bounds__(512, 2) void gru_mfma(
    const int* __restrict__ ids, const float* __restrict__ G,
    const __hip_bfloat16* __restrict__ Whi, const __hip_bfloat16* __restrict__ Wlo,
    const float* __restrict__ b_hh, float* __restrict__ ha, float* __restrict__ hc)
{
    __shared__ uint4 sh[2][2][32][16];
    __shared__ int sids[32 * TT];

    const int tid = threadIdx.x;
    const int src = blockIdx.x & 1;
    const int b0 = (blockIdx.x >> 1) * 32;
    const float* Gs = G + (size_t)src * VV * 384;
    float* hout = src ? hc : ha;

    const int lane = tid & 63;
    const int w = tid >> 6;
    const int nc0 = w * 16;
    const int mcol = lane & 15;
    const int quad = lane >> 4;

    for (int idx = tid; idx < 32 * TT; idx += 512)
        sids[idx] = ids[b0 * TT + idx];

    {
        uint4 z; z.x = z.y = z.z = z.w = 0u;
        uint4* p = &sh[0][0][0][0];
        for (int idx = tid; idx < 2 * 32 * 16; idx += 512) p[idx] = z;
    }

    short8 bh[3][4], bl[3][4];
#pragma unroll
    for (int g = 0; g < 3; ++g)
#pragma unroll
        for (int kk = 0; kk < 4; ++kk) {
            int row = g * 128 + nc0 + mcol;
            uint4 vh = *((const uint4*)Whi + row * 16 + kk * 4 + quad);
            uint4 vl = *((const uint4*)Wlo + row * 16 + kk * 4 + quad);
            bh[g][kk] = u4s8(vh);
            bl[g][kk] = u4s8(vl);
        }

    const int j = nc0 + mcol;
    const float bhn = L2E2 * b_hh[256 + j];
    const float* gbase = Gs + 3 * j;

    f4 hreg[2];
    hreg[0] = (f4){0.f, 0.f, 0.f, 0.f};
    hreg[1] = (f4){0.f, 0.f, 0.f, 0.f};

    __syncthreads();

    G3 gc[2][4];
#pragma unroll
    for (int mt = 0; mt < 2; ++mt)
#pragma unroll
        for (int reg = 0; reg < 4; ++reg) {
            int m = mt * 16 + quad * 4 + reg;
            int id = sids[m * TT + 0];
            gc[mt][reg] = *(const G3*)(gbase + (size_t)id * 384);
        }

    const int s_slot = j >> 3;
    const int jb = j & 7;

    int buf = 0;
#pragma unroll 1
    for (int t = 0; t < TT; ++t) {
        f4 acc[3][2];
#pragma unroll
        for (int g = 0; g < 3; ++g)
#pragma unroll
            for (int mt = 0; mt < 2; ++mt) acc[g][mt] = (f4){0.f, 0.f, 0.f, 0.f};

#pragma unroll
        for (int mt = 0; mt < 2; ++mt)
#pragma unroll
            for (int kk = 0; kk < 4; ++kk) {
                int m = mt * 16 + mcol;
                int phys = (kk * 4 + quad) ^ mcol;
                uint4 avh = sh[buf][0][m][phys];
                uint4 avl = sh[buf][1][m][phys];
                short8 ah = u4s8(avh), al = u4s8(avl);
#pragma unroll
                for (int g = 0; g < 3; ++g) {
                    MFMA16(acc[g][mt], ah, bh[g][kk]);
                    MFMA16(acc[g][mt], ah, bl[g][kk]);
                    MFMA16(acc[g][mt], al, bh[g][kk]);
                }
            }

        const int nbuf = buf ^ 1;
#pragma unroll
        for (int mt = 0; mt < 2; ++mt) {
            float hv4[4];
#pragma unroll
            for (int reg = 0; reg < 4; ++reg) {
                G3 g = gc[mt][reg];
                float rr = rcpf_(1.f + exp2f_(-(acc[0][mt][reg] + g.r)));
                float zz = rcpf_(1.f + exp2f_(-(acc[1][mt][reg] + g.z)));
                float y  = g.n + rr * (acc[2][mt][reg] + bhn);
                float nn = 1.f - 2.f * rcpf_(exp2f_(y) + 1.f);
                float hv = fmaf(zz, hreg[mt][reg] - nn, nn);
                hreg[mt][reg] = hv;
                hv4[reg] = hv;

                int m = mt * 16 + quad * 4 + reg;
                hout[((size_t)(b0 + m) * TT + t) * HH + j] = hv;
            }
#pragma unroll
            for (int pr = 0; pr < 2; ++pr) {
                unsigned Hp, Lp;
                split2(hv4[pr * 2], hv4[pr * 2 + 1], Hp, Lp);
#pragma unroll
                for (int k = 0; k < 2; ++k) {
                    int m = mt * 16 + quad * 4 + pr * 2 + k;
                    int phys = s_slot ^ (m & 15);
                    unsigned short hb = (unsigned short)(k ? (Hp >> 16) : Hp);
                    unsigned short lb = (unsigned short)(k ? (Lp >> 16) : Lp);
                    ((unsigned short*)&sh[nbuf][0][m][phys])[jb] = hb;
                    ((unsigned short*)&sh[nbuf][1][m][phys])[jb] = lb;
                }
            }
        }

        if (t < TT - 1) {
#pragma unroll
            for (int mt = 0; mt < 2; ++mt)
#pragma unroll
                for (int reg = 0; reg < 4; ++reg) {
                    int m = mt * 16 + quad * 4 + reg;
                    int id = sids[m * TT + t + 1];
                    gc[mt][reg] = *(const G3*)(gbase + (size_t)id * 384);
                }
        }
        barrier_lds();
        buf ^= 1;
    }
}

// ---------- attention + classifier: LDS time-multiplexed, 52.6 KB -> 3 blocks/CU ----------
// Region lifetimes (disjoint -> overlaid):
//   [0,24576)  ha staging (ph1-2) -> hcT hi/lo [0,32768) (ph3-5) -> PV-out [0,24576) (ph6)
//   [32768,..) SM 40x49 f32 (ph2-4) + SW 40 rows (ph4-5)  -> slog 40x113 f32 (ph6-7)
//   ZROW: shared 128B zero row backing SW rows 40-47 / SM rows >=40 elimination.
#define AT_HA      0
#define AT_HA_LO   12288
#define AT_HCT     0
#define AT_HCT_LO  16384
#define AT_PV      0
#define AT_PV_LO   12288
#define AT_SM      32768
#define AT_SW      40608
#define AT_SW_LO   45728
#define AT_ZROW    50848
#define AT_SLOG    32768
#define AT_PARTM   50976
#define AT_PARTD   51616
#define AT_SMX     52256
#define AT_SDI     52416
#define AT_TOTAL   52576

__global__ __launch_bounds__(256, 3) void attn_cls_mfma(
    const float* __restrict__ ha, const float* __restrict__ hc,
    const unsigned short* __restrict__ WcH, const unsigned short* __restrict__ WcL,
    const float* __restrict__ b_cls, float* __restrict__ out)
{
    __shared__ __attribute__((aligned(16))) char smem[AT_TOTAL];
    const int tid = threadIdx.x;
    const int lane = tid & 63;
    const int w = tid >> 6;
    const int quad = lane >> 4;
    const int col = lane & 15;
    const size_t b = blockIdx.x;

    float* sm    = (float*)(smem + AT_SM);
    float* slog  = (float*)(smem + AT_SLOG);
    float* partM = (float*)(smem + AT_PARTM);
    float* partD = (float*)(smem + AT_PARTD);
    float* sMX   = (float*)(smem + AT_SMX);
    float* sDI   = (float*)(smem + AT_SDI);

    const int ntc0 = (w < 3) ? w : 3;
    const int ntc1 = (w < 3) ? w + 4 : 3;
    uint4 bw[2][4][2];
    float bcv[2];
    {
        int nts[2] = {ntc0, ntc1};
#pragma unroll
        for (int which = 0; which < 2; ++which) {
            int row = nts[which] * 16 + col;
#pragma unroll
            for (int kk = 0; kk < 4; ++kk) {
                bw[which][kk][0] = *((const uint4*)WcH + row * 16 + kk * 4 + quad);
                bw[which][kk][1] = *((const uint4*)WcL + row * 16 + kk * 4 + quad);
            }
            bcv[which] = (row < CC) ? b_cls[row] : 0.f;
        }
    }

    // ---- phase 1: stage ha (hi/lo, swizzled) + zero pad rows + ZROW ----
    {
        const float4* hab = (const float4*)(ha + b * TT * HH);
#pragma unroll
        for (int i = 0; i < 5; ++i) {
            int f4i = tid + 256 * i;
            int row = f4i >> 5, q = f4i & 31;
            float4 v = hab[f4i];
            uint2 Hw, Lw;
            split2(v.x, v.y, Hw.x, Lw.x);
            split2(v.z, v.w, Hw.y, Lw.y);
            int phys = (q >> 1) ^ (row & 15);
            int off = row * 256 + phys * 16 + (q & 1) * 8;
            *(uint2*)(smem + AT_HA + off) = Hw;
            *(uint2*)(smem + AT_HA_LO + off) = Lw;
        }
        uint4 z; z.x = z.y = z.z = z.w = 0u;
        if (tid < 128) {
            int row = 40 + (tid >> 4), c = tid & 15;
            *(uint4*)(smem + AT_HA + row * 256 + c * 16) = z;
            *(uint4*)(smem + AT_HA_LO + row * 256 + c * 16) = z;
        }
        if (tid < 8) ((uint4*)(smem + AT_ZROW))[tid] = z;
    }
    __syncthreads();

    // ---- phase 2: QK^T (3 waves), write sm rows < 40 ----
    if (w < 3) {
        const int mt = w;
        uint4 aH[4], aL[4];
#pragma unroll
        for (int kk = 0; kk < 4; ++kk) {
            int phys = (kk * 4 + quad) ^ col;
            int off = (mt * 16 + col) * 256 + phys * 16;
            aH[kk] = *(uint4*)(smem + AT_HA + off);
            aL[kk] = *(uint4*)(smem + AT_HA_LO + off);
        }
        f4 acc[3];
#pragma unroll
        for (int nt = 0; nt < 3; ++nt) acc[nt] = (f4){0.f, 0.f, 0.f, 0.f};
#pragma unroll
        for (int kk = 0; kk < 4; ++kk) {
            short8 ah = u4s8(aH[kk]), al = u4s8(aL[kk]);
#pragma unroll
            for (int nt = 0; nt < 3; ++nt) {
                int phys = (kk * 4 + quad) ^ col;
                int off = (nt * 16 + col) * 256 + phys * 16;
                short8 bH = u4s8(*(uint4*)(smem + AT_HA + off));
                short8 bL = u4s8(*(uint4*)(smem + AT_HA_LO + off));
                MFMA16(acc[nt], ah, bH);
                MFMA16(acc[nt], ah, bL);
                MFMA16(acc[nt], al, bH);
            }
        }
#pragma unroll
        for (int nt = 0; nt < 3; ++nt)
#pragma unroll
            for (int r = 0; r < 4; ++r) {
                int row = mt * 16 + quad * 4 + r;
                if (row < 40) sm[row * 49 + nt * 16 + col] = acc[nt][r];
            }
    }
    __syncthreads();

    // ---- phase 3: hcT staging into [0,32768) (ha dead) + row-softmax partials ----
    {
        const float* hcb = hc + b * TT * HH;
        for (int task = tid; task < 640; task += 256) {
            int h = task & 127, c = task >> 7;
            float x[8];
#pragma unroll
            for (int jj = 0; jj < 8; ++jj) x[jj] = hcb[(c * 8 + jj) * HH + h];
            uint4 Hq, Lq;
            split2(x[0], x[1], Hq.x, Lq.x);
            split2(x[2], x[3], Hq.y, Lq.y);
            split2(x[4], x[5], Hq.z, Lq.z);
            split2(x[6], x[7], Hq.w, Lq.w);
            int phys = c ^ (h & 7);
            *(uint4*)(smem + AT_HCT + h * 128 + phys * 16) = Hq;
            *(uint4*)(smem + AT_HCT_LO + h * 128 + phys * 16) = Lq;
        }
        for (int task = tid; task < 384; task += 256) {
            int h = task & 127, c = 5 + (task >> 7);
            int phys = c ^ (h & 7);
            uint4 z; z.x = z.y = z.z = z.w = 0u;
            *(uint4*)(smem + AT_HCT + h * 128 + phys * 16) = z;
            *(uint4*)(smem + AT_HCT_LO + h * 128 + phys * 16) = z;
        }
    }
    if (tid < 160) {
        int t = tid >> 2, p = tid & 3;
        const float* row = sm + t * 49 + p * 10;
        float M = row[0];
#pragma unroll
        for (int i = 1; i < 10; ++i) M = fmaxf(M, row[i]);
        float D = 0.f;
#pragma unroll
        for (int i = 0; i < 10; ++i) D += __expf(row[i] - M);
        partM[t * 4 + p] = M;
        partD[t * 4 + p] = D;
    }
    __syncthreads();
    if (tid < 40) {
        float M = partM[tid * 4];
        M = fmaxf(M, partM[tid * 4 + 1]); M = fmaxf(M, partM[tid * 4 + 2]); M = fmaxf(M, partM[tid * 4 + 3]);
        float D = 0.f;
#pragma unroll
        for (int p = 0; p < 4; ++p) D += partD[tid * 4 + p] * __expf(partM[tid * 4 + p] - M);
        sMX[tid] = M;
        sDI[tid] = rcpf_(D);
    }
    __syncthreads();

    // ---- phase 4: W matrix (40 rows only) ----
    for (int task = tid; task < 320; task += 256) {
        int s = task >> 3, c = task & 7;
        uint4 Hq, Lq;
        if (c >= 5) {
            Hq.x = Hq.y = Hq.z = Hq.w = 0u; Lq = Hq;
        } else {
            const float* srow = sm + s * 49 + c * 8;
            float wv[8];
#pragma unroll
            for (int jj = 0; jj < 8; ++jj) {
                int t = c * 8 + jj;
                wv[jj] = __expf(srow[jj] - sMX[t]) * sDI[t];
            }
            split2(wv[0], wv[1], Hq.x, Lq.x);
            split2(wv[2], wv[3], Hq.y, Lq.y);
            split2(wv[4], wv[5], Hq.z, Lq.z);
            split2(wv[6], wv[7], Hq.w, Lq.w);
        }
        int phys = c ^ (s & 7);
        *(uint4*)(smem + AT_SW + s * 128 + phys * 16) = Hq;
        *(uint4*)(smem + AT_SW_LO + s * 128 + phys * 16) = Lq;
    }
    __syncthreads();

    // ---- phase 5: PV (A rows >= 40 read the shared zero row) ----
    {
        uint4 aH[3][2], aL[3][2];
#pragma unroll
        for (int mt = 0; mt < 3; ++mt)
#pragma unroll
            for (int kk = 0; kk < 2; ++kk) {
                int s = mt * 16 + col;
                int phys = (kk * 4 + quad) ^ (s & 7);
                if (s < 40) {
                    aH[mt][kk] = *(uint4*)(smem + AT_SW + s * 128 + phys * 16);
                    aL[mt][kk] = *(uint4*)(smem + AT_SW_LO + s * 128 + phys * 16);
                } else {
                    aH[mt][kk] = *(uint4*)(smem + AT_ZROW + phys * 16);
                    aL[mt][kk] = aH[mt][kk];
                }
            }
        f4 acc[3][2];
#pragma unroll
        for (int mt = 0; mt < 3; ++mt) { acc[mt][0] = (f4){0,0,0,0}; acc[mt][1] = (f4){0,0,0,0}; }
#pragma unroll
        for (int which = 0; which < 2; ++which) {
            int nt = w + which * 4;
            int hrow = nt * 16 + col;
#pragma unroll
            for (int kk = 0; kk < 2; ++kk) {
                int phys = (kk * 4 + quad) ^ (hrow & 7);
                short8 bH = u4s8(*(uint4*)(smem + AT_HCT + hrow * 128 + phys * 16));
                short8 bL = u4s8(*(uint4*)(smem + AT_HCT_LO + hrow * 128 + phys * 16));
#pragma unroll
                for (int mt = 0; mt < 3; ++mt) {
                    short8 ah = u4s8(aH[mt][kk]), al = u4s8(aL[mt][kk]);
                    MFMA16(acc[mt][which], ah, bH);
                    MFMA16(acc[mt][which], ah, bL);
                    MFMA16(acc[mt][which], al, bH);
                }
            }
        }
        __syncthreads();   // all hcT/SW reads done -> safe to overwrite [0,24576)
#pragma unroll
        for (int which = 0; which < 2; ++which) {
            int h = (w + which * 4) * 16 + col;
            int chunk = h >> 3, hb7 = (h & 7) * 2;
#pragma unroll
            for (int mt = 0; mt < 3; ++mt)
#pragma unroll
                for (int pr = 0; pr < 2; ++pr) {
                    unsigned Hp, Lp;
                    split2(acc[mt][which][pr * 2], acc[mt][which][pr * 2 + 1], Hp, Lp);
#pragma unroll
                    for (int k = 0; k < 2; ++k) {
                        int s = mt * 16 + quad * 4 + pr * 2 + k;
                        int phys = chunk ^ (s & 15);
                        *(unsigned short*)(smem + AT_PV + s * 256 + phys * 16 + hb7) =
                            (unsigned short)(k ? (Hp >> 16) : Hp);
                        *(unsigned short*)(smem + AT_PV_LO + s * 256 + phys * 16 + hb7) =
                            (unsigned short)(k ? (Lp >> 16) : Lp);
                    }
                }
        }
    }
    __syncthreads();

    // ---- phase 6: classifier; slog overlays SM+SW (both dead) ----
    {
        f4 acc[3][2];
#pragma unroll
        for (int mt = 0; mt < 3; ++mt) { acc[mt][0] = (f4){0,0,0,0}; acc[mt][1] = (f4){0,0,0,0}; }
#pragma unroll
        for (int kk = 0; kk < 4; ++kk)
#pragma unroll
            for (int mt = 0; mt < 3; ++mt) {
                int s = mt * 16 + col;
                int phys = (kk * 4 + quad) ^ (s & 15);
                short8 ah = u4s8(*(uint4*)(smem + AT_PV + s * 256 + phys * 16));
                short8 al = u4s8(*(uint4*)(smem + AT_PV_LO + s * 256 + phys * 16));
#pragma unroll
                for (int which = 0; which < 2; ++which) {
                    MFMA16(acc[mt][which], ah, u4s8(bw[which][kk][0]));
                    MFMA16(acc[mt][which], ah, u4s8(bw[which][kk][1]));
                    MFMA16(acc[mt][which], al, u4s8(bw[which][kk][0]));
                }
            }
        __syncthreads();
        int nts[2] = {ntc0, ntc1};
#pragma unroll
        for (int which = 0; which < 2; ++which) {
            int c = nts[which] * 16 + col;
#pragma unroll
            for (int mt = 0; mt < 3; ++mt)
#pragma unroll
                for (int r = 0; r < 4; ++r) {
                    int row = mt * 16 + quad * 4 + r;
                    if (row < 40) slog[row * 113 + c] = acc[mt][which][r] + bcv[which];
                }
        }
    }
    __syncthreads();

    // ---- phase 7: class softmax + output ----
    if (tid < 160) {
        int s = tid >> 2, p = tid & 3;
        int c0 = p * 26;
        int c1 = (c0 + 26 < CC) ? c0 + 26 : CC;
        const float* row = slog + s * 113;
        float M = row[c0];
        for (int c = c0 + 1; c < c1; ++c) M = fmaxf(M, row[c]);
        float D = 0.f;
        for (int c = c0; c < c1; ++c) D += __expf(row[c] - M);
        partM[s * 4 + p] = M;
        partD[s * 4 + p] = D;
    }
    __syncthreads();
    if (tid < 40) {
        float M = partM[tid * 4];
        M = fmaxf(M, partM[tid * 4 + 1]); M = fmaxf(M, partM[tid * 4 + 2]); M = fmaxf(M, partM[tid * 4 + 3]);
        float D = 0.f;
#pragma unroll
        for (int p = 0; p < 4; ++p) D += partD[tid * 4 + p] * __expf(partM[tid * 4 + p] - M);
        sMX[tid] = M;
        sDI[tid] = rcpf_(D);
    }
    __syncthreads();

    {
        int c = tid & 127, s0 = tid >> 7;
        if (c < CC) {
            float* ob = out + b * TT * CC;
            for (int s = s0; s < TT; s += 2)
                ob[s * CC + c] = __expf(slog[s * 113 + c] - sMX[s]) * sDI[s];
        }
    }
}

extern "C" void kernel_launch(void* const* d_in, const int* in_sizes, int n_in,
                              void* d_out, int out_size, void* d_ws, size_t ws_size,
                              hipStream_t stream) {
    const int*   ids   = (const int*)d_in[0];
    const float* emb_c = (const float*)d_in[1];
    const float* emb_a = (const float*)d_in[2];
    const float* W_ih  = (const float*)d_in[3];
    const float* W_hh  = (const float*)d_in[4];
    const float* b_ih  = (const float*)d_in[5];
    const float* b_hh  = (const float*)d_in[6];
    const float* W_cls = (const float*)d_in[7];
    const float* b_cls = (const float*)d_in[8];
    float* out = (float*)d_out;

    float* ha = (float*)d_ws;                               // [B][T][H] fp32
    float* hc = ha + (size_t)BB * TT * HH;                  // [B][T][H] fp32
    float* G  = hc + (size_t)BB * TT * HH;                  // [2][V][128][3] fp32 (pre-scaled)
    __hip_bfloat16* Whi = (__hip_bfloat16*)(G + (size_t)2 * VV * 384);
    __hip_bfloat16* Wlo = Whi + 384 * HH;
    unsigned short* WcH = (unsigned short*)(Wlo + 384 * HH);
    unsigned short* WcL = WcH + 112 * HH;
    unsigned short* WihH = WcL + 112 * HH;
    unsigned short* WihL = WihH + 384 * HH;

    prep_whh<<<(384 * HH + 255) / 256, 256, 0, stream>>>(W_hh, (unsigned short*)Whi, (unsigned short*)Wlo);
    prep_bf16split<<<(384 * HH + 255) / 256, 256, 0, stream>>>(W_ih, WihH, WihL, 384 * HH);
    prep_wcls<<<(112 * HH + 255) / 256, 256, 0, stream>>>(W_cls, WcH, WcL);
    prep_G_mfma<<<dim3((VV + 31) / 32, 2), 256, 0, stream>>>(emb_a, emb_c, WihH, WihL, b_ih, b_hh, G);
    gru_mfma<<<dim3(BB / 32 * 2), 512, 0, stream>>>(ids, G, Whi, Wlo, b_hh, ha, hc);
    attn_cls_mfma<<<BB, 256, 0, stream>>>(ha, hc, WcH, WcL, b_cls, out);
}